// Round 3
// baseline (132.089 us; speedup 1.0000x reference)
//
#include <hip/hip_runtime.h>

#define NB 32
#define NT 512
#define NC 96                     // float4 per frame (D = 384)
#define NFRAMES 2048              // T * MAX_DUR
#define SLICES 16                 // blocks per batch row
#define FPS (NFRAMES / SLICES)    // 128 frames per slice
#define ITERS (FPS * NC / NT)     // 24 float4 per thread

// One block per (row, slice). Redundant per-block scan of the row's durations
// (cheap: 2 KB), then binary-search the slice's frame->source map, then a
// coalesced float4 copy of the slice.
__global__ __launch_bounds__(NT) void lr_fused_kernel(const int* __restrict__ ds,
                                                      const float4* __restrict__ xs,
                                                      float4* __restrict__ out) {
    __shared__ int cum[NT];
    __shared__ int sidx[FPS];
    const int t = threadIdx.x;
    const int slice = blockIdx.x;
    const int b = blockIdx.y;

    // ---- inclusive scan of durations (Hillis-Steele, 9 steps) ----
    cum[t] = ds[b * NT + t];
    __syncthreads();
    #pragma unroll
    for (int off = 1; off < NT; off <<= 1) {
        int v = (t >= off) ? cum[t - off] : 0;
        __syncthreads();
        cum[t] += v;
        __syncthreads();
    }

    int total = cum[NT - 1];          // uniform across block (barrier above)
    if (total == 0) {                 // all-zero row -> every duration = 1
        cum[t] = t + 1;               // each thread rewrites its own element
        total = NT;
    }
    __syncthreads();

    // ---- frame -> source index for this slice (upper_bound in LDS) ----
    if (t < FPS) {
        const int p = slice * FPS + t;
        int j = -1;
        if (p < total) {
            int lo = 0, hi = NT;      // smallest idx with cum[idx] > p
            while (lo < hi) {
                const int mid = (lo + hi) >> 1;
                if (cum[mid] > p) hi = mid; else lo = mid + 1;
            }
            j = lo;                   // < NT guaranteed (cum[NT-1] = total > p)
        }
        sidx[t] = j;
    }
    __syncthreads();

    // ---- coalesced copy: FPS*NC float4 per block ----
    const float4* __restrict__ xrow = xs + (size_t)b * NT * NC;
    float4* __restrict__ orow = out + ((size_t)b * NFRAMES + (size_t)slice * FPS) * NC;
    const float4 z = make_float4(0.f, 0.f, 0.f, 0.f);
    #pragma unroll
    for (int it = 0; it < ITERS; ++it) {
        const int e = it * NT + t;
        const int fr = e / NC;        // magic-mul div by 96
        const int c = e - fr * NC;
        const int j = sidx[fr];       // broadcast within wave (<=2 frames/wave)
        orow[e] = (j >= 0) ? xrow[j * NC + c] : z;
    }
}

extern "C" void kernel_launch(void* const* d_in, const int* in_sizes, int n_in,
                              void* d_out, int out_size, void* d_ws, size_t ws_size,
                              hipStream_t stream) {
    const float* xs = (const float*)d_in[0];
    const int*   ds = (const int*)d_in[1];
    float* out = (float*)d_out;
    (void)in_sizes; (void)n_in; (void)out_size; (void)d_ws; (void)ws_size;

    dim3 grid(SLICES, NB);
    lr_fused_kernel<<<grid, NT, 0, stream>>>(ds, (const float4*)xs, (float4*)out);
}